// Round 1
// baseline (517.210 us; speedup 1.0000x reference)
//
#include <hip/hip_runtime.h>
#include <hip/hip_bf16.h>
#include <stdint.h>

// MoE FFN: B=2,T=2048,D=1024,F=4096,E=8,K=2. S=4096 tokens, 8192 assignments.
#define S_TOK 4096
#define DDIM  1024
#define FDIM  4096
#define EEXP  8
#define CAP   (S_TOK * 2 + 128)   // assignment arena capacity (8192 + tile pad)

typedef __bf16 bf16x8 __attribute__((ext_vector_type(8)));
typedef float  f32x4  __attribute__((ext_vector_type(4)));
typedef unsigned short us4 __attribute__((ext_vector_type(4)));

__device__ __forceinline__ unsigned short f2bf(float f) {
    union { float f; unsigned u; } v; v.f = f;
    unsigned u = v.u;
    return (unsigned short)((u + 0x7FFFu + ((u >> 16) & 1u)) >> 16);  // RNE
}

// global -> LDS async copy, 16B per lane. LDS dest = wave-uniform base + lane*16.
// Integer-cast route (CK idiom): avoids relying on C-style addrspace casts.
__device__ __forceinline__ void gload16(const void* g, void* l) {
    auto gp = reinterpret_cast<const __attribute__((address_space(1))) uint32_t*>(
        reinterpret_cast<uintptr_t>(g));
    auto lp = reinterpret_cast<__attribute__((address_space(3))) uint32_t*>(
        static_cast<uint32_t>(reinterpret_cast<uintptr_t>(l)));
    __builtin_amdgcn_global_load_lds(gp, lp, 16, 0, 0);
}

// ---------------- small kernels ----------------

__global__ void zero_k(int* p, int n) {
    int i = threadIdx.x;
    if (i < n) p[i] = 0;
}

__global__ void cvt_bf16(const float* __restrict__ src, unsigned short* __restrict__ dst, int n4) {
    int stride = gridDim.x * blockDim.x;
    for (int i = blockIdx.x * blockDim.x + threadIdx.x; i < n4; i += stride) {
        float4 v = ((const float4*)src)[i];
        us4 o;
        o[0] = f2bf(v.x); o[1] = f2bf(v.y); o[2] = f2bf(v.z); o[3] = f2bf(v.w);
        ((us4*)dst)[i] = o;
    }
}

// Router: one wave per token, fp32 dot products (must match numpy top-2 selection).
__global__ void router_k(const float* __restrict__ x, const float* __restrict__ gw,
                         int* __restrict__ topk_e, float* __restrict__ topk_g,
                         int* __restrict__ counts) {
    int s = blockIdx.x;
    int l = threadIdx.x;
    const float* xr = x + (size_t)s * DDIM;
    float acc[EEXP];
#pragma unroll
    for (int e = 0; e < EEXP; ++e) acc[e] = 0.f;
    for (int i = 0; i < DDIM; i += 64) {
        float xv = xr[i + l];
#pragma unroll
        for (int e = 0; e < EEXP; ++e) acc[e] = fmaf(xv, gw[e * DDIM + i + l], acc[e]);
    }
#pragma unroll
    for (int e = 0; e < EEXP; ++e)
        for (int off = 32; off > 0; off >>= 1) acc[e] += __shfl_down(acc[e], off, 64);
    if (l == 0) {
        float v0 = -1e30f, v1 = -1e30f; int i0 = 0, i1 = 0;
#pragma unroll
        for (int e = 0; e < EEXP; ++e) {
            float v = acc[e];
            if (v > v0)      { v1 = v0; i1 = i0; v0 = v; i0 = e; }
            else if (v > v1) { v1 = v;  i1 = e; }
        }
        float t = expf(v1 - v0);
        float d = 1.f + t;
        topk_e[2 * s] = i0; topk_e[2 * s + 1] = i1;
        topk_g[2 * s] = 1.f / d; topk_g[2 * s + 1] = t / d;
        atomicAdd(&counts[i0], 1);
        atomicAdd(&counts[i1], 1);
    }
}

__global__ void scan_k(const int* __restrict__ counts, int* __restrict__ basep) {
    if (threadIdx.x == 0) {
        int b = 0;
        for (int e = 0; e < EEXP; ++e) { basep[e] = b; b += counts[e]; }
    }
}

__global__ void scatter_k(const int* __restrict__ topk_e, int* __restrict__ rankctr,
                          const int* __restrict__ basep, int* __restrict__ arena_token,
                          int* __restrict__ pos_of) {
    int s = blockIdx.x * blockDim.x + threadIdx.x;
    if (s >= S_TOK) return;
#pragma unroll
    for (int t = 0; t < 2; ++t) {
        int e = topk_e[2 * s + t];
        int r = atomicAdd(&rankctr[e], 1);
        int p = basep[e] + r;
        arena_token[p] = s;
        pos_of[2 * s + t] = p;
    }
}

// ---------------- MFMA GEMM (m97-style 128x128 tile, BK=32, 4 waves) ----------------
// C[m][n] = sum_k A[m][k] * B[n][k]   (both K-contiguous row-major, "BT" layout)
// EPI==1: A rows gathered via arena_token from xb; out = relu(acc + b1) -> hA (bf16)
// EPI==2: A rows contiguous in hA arena; out = acc -> outA (fp32)
template <int EPI>
__global__ __launch_bounds__(256, 2) void moe_gemm(
    const unsigned short* __restrict__ Asrc, const unsigned short* __restrict__ Bw,
    const float* __restrict__ bias, unsigned short* __restrict__ hOut,
    float* __restrict__ fOut, const int* __restrict__ arena_token,
    const int* __restrict__ counts, const int* __restrict__ basep, int Kd, int Nd) {
    int e = blockIdx.z;
    int count = counts[e];
    int m0 = blockIdx.y * 128;
    if (m0 >= count) return;
    int base = basep[e];
    int n0 = blockIdx.x * 128;
    int tid = threadIdx.x, w = tid >> 6, l = tid & 63;

    __shared__ unsigned short lsA[128 * 32];
    __shared__ unsigned short lsB[128 * 32];

    const unsigned short* pA[2];
    const unsigned short* pB[2];
#pragma unroll
    for (int i = 0; i < 2; ++i) {
        int r = i * 64 + w * 16 + (l >> 2);
        int gr = m0 + r;
        if (EPI == 1) {
            int rr = (gr < count) ? gr : (count - 1);
            int tok = arena_token[base + rr];
            pA[i] = Asrc + (size_t)tok * Kd + (l & 3) * 8;
        } else {
            pA[i] = Asrc + (size_t)(base + gr) * Kd + (l & 3) * 8;  // < CAP rows, garbage rows masked at store
        }
        pB[i] = Bw + ((size_t)e * Nd + n0 + r) * Kd + (l & 3) * 8;
    }
    char* dA = (char*)lsA + w * 1024;
    char* dB = (char*)lsB + w * 1024;
    int wm = w >> 1, wn = w & 1;
    const char* aB = (const char*)lsA + (size_t)(wm * 64 + (l & 15)) * 64 + (l >> 4) * 16;
    const char* bB = (const char*)lsB + (size_t)(wn * 64 + (l & 15)) * 64 + (l >> 4) * 16;

    f32x4 acc[4][4];
#pragma unroll
    for (int i = 0; i < 4; ++i)
#pragma unroll
        for (int j = 0; j < 4; ++j) acc[i][j] = (f32x4){0.f, 0.f, 0.f, 0.f};

    for (int k0 = 0; k0 < Kd; k0 += 32) {
        gload16(pA[0] + k0, dA);
        gload16(pA[1] + k0, dA + 4096);
        gload16(pB[0] + k0, dB);
        gload16(pB[1] + k0, dB + 4096);
        __syncthreads();  // drains vmcnt(0) per compiler barrier semantics
        bf16x8 af[4], bfr[4];
#pragma unroll
        for (int mi = 0; mi < 4; ++mi) af[mi] = *(const bf16x8*)(aB + mi * 16 * 64);
#pragma unroll
        for (int ni = 0; ni < 4; ++ni) bfr[ni] = *(const bf16x8*)(bB + ni * 16 * 64);
#pragma unroll
        for (int mi = 0; mi < 4; ++mi)
#pragma unroll
            for (int ni = 0; ni < 4; ++ni)
                acc[mi][ni] = __builtin_amdgcn_mfma_f32_16x16x32_bf16(af[mi], bfr[ni], acc[mi][ni], 0, 0, 0);
        __syncthreads();
    }

    // Epilogue. C/D layout: col = lane&15, row = (lane>>4)*4 + reg  [m89 verified]
#pragma unroll
    for (int mi = 0; mi < 4; ++mi)
#pragma unroll
        for (int ni = 0; ni < 4; ++ni)
#pragma unroll
            for (int r = 0; r < 4; ++r) {
                int rl = wm * 64 + mi * 16 + (l >> 4) * 4 + r;
                int gr = m0 + rl;
                if (gr < count) {
                    int col = n0 + wn * 64 + ni * 16 + (l & 15);
                    float v = acc[mi][ni][r];
                    if (EPI == 1) {
                        v += bias[e * Nd + col];
                        v = fmaxf(v, 0.f);
                        hOut[(size_t)(base + gr) * Nd + col] = f2bf(v);
                    } else {
                        fOut[(size_t)(base + gr) * Nd + col] = v;
                    }
                }
            }
}

// Deterministic combine: y[s] = g0*(out[p0]+b2[e0]) + g1*(out[p1]+b2[e1])
__global__ void combine_k(const float* __restrict__ outA, const float* __restrict__ b2,
                          const int* __restrict__ topk_e, const float* __restrict__ topk_g,
                          const int* __restrict__ pos_of, float* __restrict__ y) {
    int idx = blockIdx.x * blockDim.x + threadIdx.x;  // S*D/4 threads
    int s = idx >> 8;            // D/4 = 256
    int c = (idx & 255) * 4;
    int e0 = topk_e[2 * s], e1 = topk_e[2 * s + 1];
    float g0 = topk_g[2 * s], g1 = topk_g[2 * s + 1];
    int p0 = pos_of[2 * s], p1 = pos_of[2 * s + 1];
    float4 o0 = *(const float4*)(outA + (size_t)p0 * DDIM + c);
    float4 o1 = *(const float4*)(outA + (size_t)p1 * DDIM + c);
    float4 c0 = *(const float4*)(b2 + (size_t)e0 * DDIM + c);
    float4 c1 = *(const float4*)(b2 + (size_t)e1 * DDIM + c);
    float4 r;
    r.x = g0 * (o0.x + c0.x) + g1 * (o1.x + c1.x);
    r.y = g0 * (o0.y + c0.y) + g1 * (o1.y + c1.y);
    r.z = g0 * (o0.z + c0.z) + g1 * (o1.z + c1.z);
    r.w = g0 * (o0.w + c0.w) + g1 * (o1.w + c1.w);
    *(float4*)(y + (size_t)s * DDIM + c) = r;
}

extern "C" void kernel_launch(void* const* d_in, const int* in_sizes, int n_in,
                              void* d_out, int out_size, void* d_ws, size_t ws_size,
                              hipStream_t stream) {
    const float* x      = (const float*)d_in[0];
    const float* gate_w = (const float*)d_in[1];
    const float* w1     = (const float*)d_in[2];
    const float* b1     = (const float*)d_in[3];
    const float* w2     = (const float*)d_in[4];
    const float* b2     = (const float*)d_in[5];
    // d_in[6] = k (==2), compile-time constant here.

    char* p = (char*)d_ws;
    unsigned short* w1b = (unsigned short*)p; p += (size_t)EEXP * FDIM * DDIM * 2;  // 64 MB
    unsigned short* w2b = (unsigned short*)p; p += (size_t)EEXP * FDIM * DDIM * 2;  // 64 MB
    unsigned short* xb  = (unsigned short*)p; p += (size_t)S_TOK * DDIM * 2;        //  8 MB
    unsigned short* hA  = (unsigned short*)p; p += (size_t)CAP * FDIM * 2;          // 65 MB
    float* outA         = (float*)p;          p += (size_t)CAP * DDIM * 4;          // 32.5 MB
    int*   topk_e       = (int*)p;            p += S_TOK * 2 * 4;
    float* topk_g       = (float*)p;          p += S_TOK * 2 * 4;
    int*   pos_of       = (int*)p;            p += S_TOK * 2 * 4;
    int*   arena_token  = (int*)p;            p += CAP * 4;
    int*   counts       = (int*)p;            p += 64;
    int*   rankctr      = (int*)p;            p += 64;
    int*   basep        = (int*)p;            p += 64;
    (void)ws_size; (void)in_sizes; (void)n_in; (void)out_size;

    zero_k<<<1, 64, 0, stream>>>(counts, 48);  // counts + rankctr + basep (contiguous)

    cvt_bf16<<<2048, 256, 0, stream>>>(w1, w1b, EEXP * FDIM * DDIM / 4);
    cvt_bf16<<<2048, 256, 0, stream>>>(w2, w2b, EEXP * FDIM * DDIM / 4);
    cvt_bf16<<<512, 256, 0, stream>>>(x, xb, S_TOK * DDIM / 4);

    router_k<<<S_TOK, 64, 0, stream>>>(x, gate_w, topk_e, topk_g, counts);
    scan_k<<<1, 1, 0, stream>>>(counts, basep);
    scatter_k<<<S_TOK / 256, 256, 0, stream>>>(topk_e, rankctr, basep, arena_token, pos_of);

    moe_gemm<1><<<dim3(FDIM / 128, 32, EEXP), 256, 0, stream>>>(
        xb, w1b, b1, hA, nullptr, arena_token, counts, basep, DDIM, FDIM);
    moe_gemm<2><<<dim3(DDIM / 128, 32, EEXP), 256, 0, stream>>>(
        hA, w2b, nullptr, nullptr, outA, arena_token, counts, basep, FDIM, DDIM);

    combine_k<<<S_TOK * DDIM / 4 / 256, 256, 0, stream>>>(
        outA, b2, topk_e, topk_g, pos_of, (float*)d_out);
}